// Round 1
// baseline (1953.460 us; speedup 1.0000x reference)
//
#include <hip/hip_runtime.h>
#include <hip/hip_bf16.h>
#include <math.h>

#define NEXP 8
#define DDIM 1024
#define FFDIM 4096
#define NTOK 8192
#define NSLOT (NTOK * 2)
#define BM 128
#define BN 128
#define BK 32
#define MAXT ((NSLOT / BM) + NEXP) /* 136 worst-case row tiles */

typedef __attribute__((ext_vector_type(8))) __bf16 bf16x8;
typedef __attribute__((ext_vector_type(4))) float f32x4;

union BF4 { __bf16 b[4]; ushort4 u; };

__device__ __forceinline__ float gelu_exact(float v) {
    return 0.5f * v * (1.0f + erff(v * 0.70710678118654752f));
}

// ---------------- router: logits -> softmax -> top2 -> gates ----------------
__global__ __launch_bounds__(64)
void router_kernel(const float* __restrict__ x, const float* __restrict__ Wr,
                   int* __restrict__ idx2, float* __restrict__ gates2,
                   int* __restrict__ counts)
{
    int t = blockIdx.x;
    int lane = threadIdx.x;
    const float* xr = x + (size_t)t * DDIM;
    float acc[NEXP];
#pragma unroll
    for (int e = 0; e < NEXP; ++e) acc[e] = 0.f;
    for (int d = lane; d < DDIM; d += 64) {
        float xv = xr[d];
        const float* wrow = Wr + d * NEXP;
#pragma unroll
        for (int e = 0; e < NEXP; ++e) acc[e] += xv * wrow[e];
    }
#pragma unroll
    for (int e = 0; e < NEXP; ++e) {
        float v = acc[e];
        for (int off = 32; off > 0; off >>= 1) v += __shfl_xor(v, off, 64);
        acc[e] = v;
    }
    if (lane == 0) {
        float mx = acc[0];
#pragma unroll
        for (int e = 1; e < NEXP; ++e) mx = fmaxf(mx, acc[e]);
        float p[NEXP]; float s = 0.f;
#pragma unroll
        for (int e = 0; e < NEXP; ++e) { p[e] = expf(acc[e] - mx); s += p[e]; }
        float inv = 1.f / s;
#pragma unroll
        for (int e = 0; e < NEXP; ++e) p[e] *= inv;
        int i1 = 0; float p1 = p[0];
#pragma unroll
        for (int e = 1; e < NEXP; ++e) if (p[e] > p1) { p1 = p[e]; i1 = e; }
        int i2 = -1; float p2 = -1.f;
#pragma unroll
        for (int e = 0; e < NEXP; ++e) {
            if (e == i1) continue;
            if (p[e] > p2) { p2 = p[e]; i2 = e; }
        }
        // gates = softmax([p1, p2]) over the prob values (reference semantics)
        float u = expf(p2 - p1);
        float den = 1.f + u;
        float g1 = 1.f / den;
        float g2 = u / den;
        idx2[2 * t] = i1; idx2[2 * t + 1] = i2;
        gates2[2 * t] = g1; gates2[2 * t + 1] = g2;
        atomicAdd(&counts[i1], 1);
        atomicAdd(&counts[i2], 1);
    }
}

// ---------------- offsets + tile table (single thread) ----------------
__global__ void offsets_kernel(const int* __restrict__ counts, int* __restrict__ offsets,
                               int* __restrict__ cursors, int* __restrict__ tiletab)
{
    if (threadIdx.x != 0 || blockIdx.x != 0) return;
    int off = 0, idx = 0;
    for (int e = 0; e < NEXP; ++e) {
        offsets[e] = off;
        cursors[e] = 0;
        int nt = (counts[e] + BM - 1) / BM;
        for (int t = 0; t < nt; ++t) { tiletab[2 * idx] = e; tiletab[2 * idx + 1] = t; ++idx; }
        off += counts[e];
    }
    for (; idx < MAXT; ++idx) { tiletab[2 * idx] = -1; tiletab[2 * idx + 1] = 0; }
}

// ---------------- fill permutation ----------------
__global__ __launch_bounds__(256)
void fill_kernel(const int* __restrict__ idx2, const float* __restrict__ gates2,
                 const int* __restrict__ offsets, int* __restrict__ cursors,
                 int* __restrict__ perm, float* __restrict__ gate_slot)
{
    int t = blockIdx.x * 256 + threadIdx.x;
    if (t >= NTOK) return;
#pragma unroll
    for (int s = 0; s < 2; ++s) {
        int e = idx2[2 * t + s];
        int pos = atomicAdd(&cursors[e], 1);
        int slot = offsets[e] + pos;
        perm[slot] = t;
        gate_slot[slot] = gates2[2 * t + s];
    }
}

// ---------------- shared tile-header logic ----------------
__device__ __forceinline__ bool tile_header(const int* counts, const int* offsets,
                                            const int* tiletab, int e_arg, int c_arg, int CH,
                                            int& e, int& start, int& cnt, int& hbase, int& row0,
                                            int& rows_here)
{
    int rowtile;
    if (e_arg >= 0) {
        e = e_arg;
        int cbase = c_arg * CH;
        cnt = counts[e] - cbase;
        if (cnt <= 0) return false;
        if (cnt > CH) cnt = CH;
        start = offsets[e] + cbase;
        rowtile = blockIdx.y;
        hbase = start;
    } else {
        e = tiletab[2 * blockIdx.y];
        if (e < 0) return false;
        rowtile = tiletab[2 * blockIdx.y + 1];
        start = offsets[e];
        cnt = counts[e];
        hbase = 0;
    }
    row0 = rowtile * BM;
    if (row0 >= cnt) return false;
    rows_here = cnt - row0;
    if (rows_here > BM) rows_here = BM;
    return true;
}

// ---------------- GEMM1: H = gelu(X_gathered @ W1[e] + b1[e]) ----------------
__global__ __launch_bounds__(256)
void gemm1_kernel(const float* __restrict__ x, const float* __restrict__ W1,
                  const float* __restrict__ b1,
                  const int* __restrict__ perm, const int* __restrict__ counts,
                  const int* __restrict__ offsets, const int* __restrict__ tiletab,
                  __bf16* __restrict__ H,
                  int e_arg, int c_arg, int CH)
{
    __shared__ __bf16 As[BM][40];
    __shared__ __bf16 Bs[BN][40]; // transposed: [n][k]

    int e, start, cnt, hbase, row0, rows_here;
    if (!tile_header(counts, offsets, tiletab, e_arg, c_arg, CH, e, start, cnt, hbase, row0, rows_here))
        return;

    const float* W1e = W1 + (size_t)e * DDIM * FFDIM;
    const float* b1e = b1 + (size_t)e * FFDIM;
    int n0 = blockIdx.x * BN;

    int tid = threadIdx.x;
    int lane = tid & 63;
    int wid = tid >> 6;
    int wm = wid >> 1, wn = wid & 1;
    int lr = lane & 15;
    int lhi = lane >> 4;
    int lk = lhi * 8;

    f32x4 acc[4][4] = {};

    for (int k0 = 0; k0 < DDIM; k0 += BK) {
        __syncthreads();
        // stage A (gathered x rows), fp32 -> bf16
#pragma unroll
        for (int i = 0; i < 4; ++i) {
            int lin4 = tid + i * 256;
            int r = lin4 >> 3;
            int c4 = (lin4 & 7) * 4;
            BF4 pk;
            if (r < rows_here) {
                int token = perm[start + row0 + r];
                float4 v = *(const float4*)(x + (size_t)token * DDIM + k0 + c4);
                pk.b[0] = (__bf16)v.x; pk.b[1] = (__bf16)v.y;
                pk.b[2] = (__bf16)v.z; pk.b[3] = (__bf16)v.w;
            } else {
                pk.b[0] = pk.b[1] = pk.b[2] = pk.b[3] = (__bf16)0.f;
            }
            *(ushort4*)(&As[r][c4]) = pk.u;
        }
        // stage B (W1 tile), fp32 -> bf16, transposed into [n][k]
#pragma unroll
        for (int i = 0; i < 4; ++i) {
            int lin4 = tid + i * 256;
            int kr = lin4 >> 5;
            int c = (lin4 & 31) * 4;
            float4 v = *(const float4*)(W1e + (size_t)(k0 + kr) * FFDIM + n0 + c);
            Bs[c + 0][kr] = (__bf16)v.x;
            Bs[c + 1][kr] = (__bf16)v.y;
            Bs[c + 2][kr] = (__bf16)v.z;
            Bs[c + 3][kr] = (__bf16)v.w;
        }
        __syncthreads();

        bf16x8 af[4], bfr[4];
#pragma unroll
        for (int m = 0; m < 4; ++m)
            af[m] = *(const bf16x8*)(&As[wm * 64 + m * 16 + lr][lk]);
#pragma unroll
        for (int n = 0; n < 4; ++n)
            bfr[n] = *(const bf16x8*)(&Bs[wn * 64 + n * 16 + lr][lk]);
#pragma unroll
        for (int m = 0; m < 4; ++m)
#pragma unroll
            for (int n = 0; n < 4; ++n)
                acc[m][n] = __builtin_amdgcn_mfma_f32_16x16x32_bf16(af[m], bfr[n], acc[m][n], 0, 0, 0);
    }

#pragma unroll
    for (int m = 0; m < 4; ++m) {
        int rbase = wm * 64 + m * 16 + lhi * 4;
#pragma unroll
        for (int n = 0; n < 4; ++n) {
            int col = n0 + wn * 64 + n * 16 + lr;
            float bias = b1e[col];
#pragma unroll
            for (int j = 0; j < 4; ++j) {
                int rl = rbase + j;
                if (rl < rows_here) {
                    float v = acc[m][n][j] + bias;
                    H[(size_t)(start + row0 + rl - hbase) * FFDIM + col] = (__bf16)gelu_exact(v);
                }
            }
        }
    }
}

// ---------------- GEMM2: out[token] += gate * (H @ W2[e] + b2[e]) ----------------
__global__ __launch_bounds__(256)
void gemm2_kernel(const __bf16* __restrict__ H, const float* __restrict__ W2,
                  const float* __restrict__ b2,
                  const int* __restrict__ perm, const float* __restrict__ gate_slot,
                  const int* __restrict__ counts, const int* __restrict__ offsets,
                  const int* __restrict__ tiletab,
                  float* __restrict__ out,
                  int e_arg, int c_arg, int CH)
{
    __shared__ __bf16 As[BM][40];
    __shared__ __bf16 Bs[BN][40];

    int e, start, cnt, hbase, row0, rows_here;
    if (!tile_header(counts, offsets, tiletab, e_arg, c_arg, CH, e, start, cnt, hbase, row0, rows_here))
        return;

    const float* W2e = W2 + (size_t)e * FFDIM * DDIM;
    const float* b2e = b2 + (size_t)e * DDIM;
    int n0 = blockIdx.x * BN;

    int tid = threadIdx.x;
    int lane = tid & 63;
    int wid = tid >> 6;
    int wm = wid >> 1, wn = wid & 1;
    int lr = lane & 15;
    int lhi = lane >> 4;
    int lk = lhi * 8;

    f32x4 acc[4][4] = {};

    for (int k0 = 0; k0 < FFDIM; k0 += BK) {
        __syncthreads();
        // stage A from H (already bf16): 16B copies
#pragma unroll
        for (int i = 0; i < 2; ++i) {
            int lin8 = tid + i * 256;
            int r = lin8 >> 2;
            int c8 = (lin8 & 3) * 8;
            uint4 v = make_uint4(0u, 0u, 0u, 0u);
            if (r < rows_here)
                v = *(const uint4*)(H + (size_t)(start + row0 + r - hbase) * FFDIM + k0 + c8);
            *(uint4*)(&As[r][c8]) = v;
        }
        // stage B (W2 tile), fp32 -> bf16, transposed
#pragma unroll
        for (int i = 0; i < 4; ++i) {
            int lin4 = tid + i * 256;
            int kr = lin4 >> 5;
            int c = (lin4 & 31) * 4;
            float4 v = *(const float4*)(W2e + (size_t)(k0 + kr) * DDIM + n0 + c);
            Bs[c + 0][kr] = (__bf16)v.x;
            Bs[c + 1][kr] = (__bf16)v.y;
            Bs[c + 2][kr] = (__bf16)v.z;
            Bs[c + 3][kr] = (__bf16)v.w;
        }
        __syncthreads();

        bf16x8 af[4], bfr[4];
#pragma unroll
        for (int m = 0; m < 4; ++m)
            af[m] = *(const bf16x8*)(&As[wm * 64 + m * 16 + lr][lk]);
#pragma unroll
        for (int n = 0; n < 4; ++n)
            bfr[n] = *(const bf16x8*)(&Bs[wn * 64 + n * 16 + lr][lk]);
#pragma unroll
        for (int m = 0; m < 4; ++m)
#pragma unroll
            for (int n = 0; n < 4; ++n)
                acc[m][n] = __builtin_amdgcn_mfma_f32_16x16x32_bf16(af[m], bfr[n], acc[m][n], 0, 0, 0);
    }

#pragma unroll
    for (int m = 0; m < 4; ++m) {
        int rbase = wm * 64 + m * 16 + lhi * 4;
#pragma unroll
        for (int n = 0; n < 4; ++n) {
            int col = n0 + wn * 64 + n * 16 + lr;
            float bias = b2e[col];
#pragma unroll
            for (int j = 0; j < 4; ++j) {
                int rl = rbase + j;
                if (rl < rows_here) {
                    int slot = start + row0 + rl;
                    int token = perm[slot];
                    float g = gate_slot[slot];
                    float v = (acc[m][n][j] + bias) * g;
                    atomicAdd(out + (size_t)token * DDIM + col, v);
                }
            }
        }
    }
}

extern "C" void kernel_launch(void* const* d_in, const int* in_sizes, int n_in,
                              void* d_out, int out_size, void* d_ws, size_t ws_size,
                              hipStream_t stream)
{
    const float* x  = (const float*)d_in[0];
    const float* Wr = (const float*)d_in[1];
    const float* W1 = (const float*)d_in[2];
    const float* b1 = (const float*)d_in[3];
    const float* W2 = (const float*)d_in[4];
    const float* b2 = (const float*)d_in[5];
    float* out = (float*)d_out;

    char* ws = (char*)d_ws;
    int* counts   = (int*)ws;                 // 8
    int* offsets  = counts + 8;               // 8
    int* cursors  = offsets + 8;              // 8
    int* tiletab  = cursors + 8;              // 2*MAXT
    int* idx2     = tiletab + 2 * MAXT;       // 2*NTOK
    float* gates2 = (float*)(idx2 + 2 * NTOK);// 2*NTOK
    int* perm     = (int*)(gates2 + 2 * NTOK);// NSLOT
    float* gate_slot = (float*)(perm + NSLOT);// NSLOT
    char* hraw = (char*)(gate_slot + NSLOT);
    size_t hoff = (((size_t)(hraw - ws)) + 255) & ~(size_t)255;
    __bf16* H = (__bf16*)(ws + hoff);
    size_t avail = ws_size > hoff ? ws_size - hoff : 0;
    size_t need_big = (size_t)NSLOT * FFDIM * 2;

    hipMemsetAsync(d_out, 0, (size_t)out_size * sizeof(float), stream);
    hipMemsetAsync(counts, 0, 8 * sizeof(int), stream);

    router_kernel<<<NTOK, 64, 0, stream>>>(x, Wr, idx2, gates2, counts);
    offsets_kernel<<<1, 1, 0, stream>>>(counts, offsets, cursors, tiletab);
    fill_kernel<<<NTOK / 256, 256, 0, stream>>>(idx2, gates2, offsets, cursors, perm, gate_slot);

    if (avail >= need_big) {
        dim3 g1(FFDIM / BN, MAXT, 1);
        gemm1_kernel<<<g1, 256, 0, stream>>>(x, W1, b1, perm, counts, offsets, tiletab, H, -1, 0, 0);
        dim3 g2(DDIM / BN, MAXT, 1);
        gemm2_kernel<<<g2, 256, 0, stream>>>(H, W2, b2, perm, gate_slot, counts, offsets, tiletab, out, -1, 0, 0);
    } else {
        size_t rowbytes = (size_t)FFDIM * 2;
        long long chl = (long long)((avail / rowbytes) / BM) * BM;
        int CH = (int)(chl > 2048 ? 2048 : chl);
        if (CH >= BM) {
            int nchunk = (NSLOT + CH - 1) / CH;
            for (int e = 0; e < NEXP; ++e) {
                for (int c = 0; c < nchunk; ++c) {
                    dim3 g1(FFDIM / BN, CH / BM, 1);
                    gemm1_kernel<<<g1, 256, 0, stream>>>(x, W1, b1, perm, counts, offsets, tiletab, H, e, c, CH);
                    dim3 g2(DDIM / BN, CH / BM, 1);
                    gemm2_kernel<<<g2, 256, 0, stream>>>(H, W2, b2, perm, gate_slot, counts, offsets, tiletab, out, e, c, CH);
                }
            }
        }
    }
}

// Round 2
// 1006.536 us; speedup vs baseline: 1.9408x; 1.9408x over previous
//
#include <hip/hip_runtime.h>
#include <hip/hip_bf16.h>
#include <math.h>

#define NEXP 8
#define DDIM 1024
#define FFDIM 4096
#define NTOK 8192
#define NSLOT (NTOK * 2)
#define BM 128
#define BN 128
#define BK 64
#define MAXT ((NSLOT / BM) + NEXP) /* 136 worst-case row tiles */

typedef __attribute__((ext_vector_type(8))) __bf16 bf16x8;
typedef __attribute__((ext_vector_type(4))) float f32x4;

union BF8 { __bf16 b[8]; uint4 u; bf16x8 v; };

__device__ __forceinline__ float gelu_exact(float v) {
    return 0.5f * v * (1.0f + erff(v * 0.70710678118654752f));
}

// Swizzled byte offset inside a [rows][64 bf16] tile (128B rows).
// XOR of byte-bits 4..6 with (row&7): bijective per row, spreads the
// 16B slots of 8 consecutive rows across all 32 banks (T2 recipe).
__device__ __forceinline__ int swz(int row, int colb) {
    return row * 128 + (colb ^ ((row & 7) << 4));
}

// ---------------- router: logits -> softmax -> top2 -> gates ----------------
__global__ __launch_bounds__(64)
void router_kernel(const float* __restrict__ x, const float* __restrict__ Wr,
                   int* __restrict__ idx2, float* __restrict__ gates2,
                   int* __restrict__ counts)
{
    int t = blockIdx.x;
    int lane = threadIdx.x;
    const float* xr = x + (size_t)t * DDIM;
    float acc[NEXP];
#pragma unroll
    for (int e = 0; e < NEXP; ++e) acc[e] = 0.f;
    for (int d = lane; d < DDIM; d += 64) {
        float xv = xr[d];
        const float* wrow = Wr + d * NEXP;
#pragma unroll
        for (int e = 0; e < NEXP; ++e) acc[e] += xv * wrow[e];
    }
#pragma unroll
    for (int e = 0; e < NEXP; ++e) {
        float v = acc[e];
        for (int off = 32; off > 0; off >>= 1) v += __shfl_xor(v, off, 64);
        acc[e] = v;
    }
    if (lane == 0) {
        float mx = acc[0];
#pragma unroll
        for (int e = 1; e < NEXP; ++e) mx = fmaxf(mx, acc[e]);
        float p[NEXP]; float s = 0.f;
#pragma unroll
        for (int e = 0; e < NEXP; ++e) { p[e] = expf(acc[e] - mx); s += p[e]; }
        float inv = 1.f / s;
#pragma unroll
        for (int e = 0; e < NEXP; ++e) p[e] *= inv;
        int i1 = 0; float p1 = p[0];
#pragma unroll
        for (int e = 1; e < NEXP; ++e) if (p[e] > p1) { p1 = p[e]; i1 = e; }
        int i2 = -1; float p2 = -1.f;
#pragma unroll
        for (int e = 0; e < NEXP; ++e) {
            if (e == i1) continue;
            if (p[e] > p2) { p2 = p[e]; i2 = e; }
        }
        float u = expf(p2 - p1);
        float den = 1.f + u;
        float g1 = 1.f / den;
        float g2 = u / den;
        idx2[2 * t] = i1; idx2[2 * t + 1] = i2;
        gates2[2 * t] = g1; gates2[2 * t + 1] = g2;
        atomicAdd(&counts[i1], 1);
        atomicAdd(&counts[i2], 1);
    }
}

// ---------------- offsets + tile table (single thread) ----------------
__global__ void offsets_kernel(const int* __restrict__ counts, int* __restrict__ offsets,
                               int* __restrict__ cursors, int* __restrict__ tiletab)
{
    if (threadIdx.x != 0 || blockIdx.x != 0) return;
    int off = 0, idx = 0;
    for (int e = 0; e < NEXP; ++e) {
        offsets[e] = off;
        cursors[e] = 0;
        int nt = (counts[e] + BM - 1) / BM;
        for (int t = 0; t < nt; ++t) { tiletab[2 * idx] = e; tiletab[2 * idx + 1] = t; ++idx; }
        off += counts[e];
    }
    for (; idx < MAXT; ++idx) { tiletab[2 * idx] = -1; tiletab[2 * idx + 1] = 0; }
}

// ---------------- fill permutation ----------------
__global__ __launch_bounds__(256)
void fill_kernel(const int* __restrict__ idx2, const float* __restrict__ gates2,
                 const int* __restrict__ offsets, int* __restrict__ cursors,
                 int* __restrict__ perm, float* __restrict__ gate_slot)
{
    int t = blockIdx.x * 256 + threadIdx.x;
    if (t >= NTOK) return;
#pragma unroll
    for (int s = 0; s < 2; ++s) {
        int e = idx2[2 * t + s];
        int pos = atomicAdd(&cursors[e], 1);
        int slot = offsets[e] + pos;
        perm[slot] = t;
        gate_slot[slot] = gates2[2 * t + s];
    }
}

// ---------------- shared tile-header logic ----------------
__device__ __forceinline__ bool tile_header(const int* counts, const int* offsets,
                                            const int* tiletab, int e_arg, int c_arg, int CH,
                                            int& e, int& start, int& cnt, int& hbase, int& row0,
                                            int& rows_here)
{
    int rowtile;
    if (e_arg >= 0) {
        e = e_arg;
        int cbase = c_arg * CH;
        cnt = counts[e] - cbase;
        if (cnt <= 0) return false;
        if (cnt > CH) cnt = CH;
        start = offsets[e] + cbase;
        rowtile = blockIdx.y;
        hbase = start;
    } else {
        e = tiletab[2 * blockIdx.y];
        if (e < 0) return false;
        rowtile = tiletab[2 * blockIdx.y + 1];
        start = offsets[e];
        cnt = counts[e];
        hbase = 0;
    }
    row0 = rowtile * BM;
    if (row0 >= cnt) return false;
    rows_here = cnt - row0;
    if (rows_here > BM) rows_here = BM;
    return true;
}

// ---------------- GEMM1: H = gelu(X_gathered @ W1[e] + b1[e]) ----------------
__global__ __launch_bounds__(256)
void gemm1_kernel(const float* __restrict__ x, const float* __restrict__ W1,
                  const float* __restrict__ b1,
                  const int* __restrict__ perm, const int* __restrict__ counts,
                  const int* __restrict__ offsets, const int* __restrict__ tiletab,
                  __bf16* __restrict__ H,
                  int e_arg, int c_arg, int CH)
{
    __shared__ __align__(16) char smem[(BM + BN) * 128]; // 32 KiB
    char* As = smem;             // [128 rows][64 bf16] swizzled
    char* Bs = smem + BM * 128;  // [128 n-rows][64 bf16] swizzled (B^T)

    int e, start, cnt, hbase, row0, rows_here;
    if (!tile_header(counts, offsets, tiletab, e_arg, c_arg, CH, e, start, cnt, hbase, row0, rows_here))
        return;

    const float* W1e = W1 + (size_t)e * DDIM * FFDIM;
    const float* b1e = b1 + (size_t)e * FFDIM;
    int n0 = blockIdx.x * BN;

    int tid = threadIdx.x;
    int lane = tid & 63;
    int wid = tid >> 6;
    int wm = wid >> 1, wn = wid & 1;
    int lr = lane & 15;
    int lhi = lane >> 4;

    // staging roles
    int ar = tid >> 1, ach = tid & 1;        // A: row, 32-col half
    int token = -1;
    if (ar < rows_here) token = perm[start + row0 + ar];
    const float* arow = x + (size_t)(token < 0 ? 0 : token) * DDIM + ach * 32;

    int bn = tid & 127, bkh = tid >> 7;      // B: column n, 32-k half
    const float* bcol = W1e + (size_t)bkh * 32 * FFDIM + n0 + bn;

    f32x4 acc[4][4] = {};

    for (int k0 = 0; k0 < DDIM; k0 += BK) {
        __syncthreads();
        // ---- stage A: gathered x rows, fp32 -> bf16, vector LDS writes ----
        {
            BF8 pk[4];
            if (token >= 0) {
                const float4* p = (const float4*)(arow + k0);
#pragma unroll
                for (int i = 0; i < 4; ++i) {
                    float4 v0 = p[2 * i], v1 = p[2 * i + 1];
                    pk[i].b[0] = (__bf16)v0.x; pk[i].b[1] = (__bf16)v0.y;
                    pk[i].b[2] = (__bf16)v0.z; pk[i].b[3] = (__bf16)v0.w;
                    pk[i].b[4] = (__bf16)v1.x; pk[i].b[5] = (__bf16)v1.y;
                    pk[i].b[6] = (__bf16)v1.z; pk[i].b[7] = (__bf16)v1.w;
                }
            } else {
#pragma unroll
                for (int i = 0; i < 4; ++i) pk[i].u = make_uint4(0u, 0u, 0u, 0u);
            }
#pragma unroll
            for (int i = 0; i < 4; ++i)
                *(uint4*)(As + swz(ar, ach * 64 + i * 16)) = pk[i].u;
        }
        // ---- stage B: W1 columns (coalesced across lanes), transpose-free ----
        {
            float f[32];
            const float* p = bcol + (size_t)k0 * FFDIM;
#pragma unroll
            for (int j = 0; j < 32; ++j) f[j] = p[(size_t)j * FFDIM];
#pragma unroll
            for (int i = 0; i < 4; ++i) {
                BF8 pk;
#pragma unroll
                for (int q = 0; q < 8; ++q) pk.b[q] = (__bf16)f[i * 8 + q];
                *(uint4*)(Bs + swz(bn, bkh * 64 + i * 16)) = pk.u;
            }
        }
        __syncthreads();

#pragma unroll
        for (int kk = 0; kk < 2; ++kk) {
            bf16x8 af[4], bfr[4];
#pragma unroll
            for (int m = 0; m < 4; ++m)
                af[m] = *(const bf16x8*)(As + swz(wm * 64 + m * 16 + lr, kk * 64 + lhi * 16));
#pragma unroll
            for (int n = 0; n < 4; ++n)
                bfr[n] = *(const bf16x8*)(Bs + swz(wn * 64 + n * 16 + lr, kk * 64 + lhi * 16));
#pragma unroll
            for (int m = 0; m < 4; ++m)
#pragma unroll
                for (int n = 0; n < 4; ++n)
                    acc[m][n] = __builtin_amdgcn_mfma_f32_16x16x32_bf16(af[m], bfr[n], acc[m][n], 0, 0, 0);
        }
    }

    float bias[4];
#pragma unroll
    for (int n = 0; n < 4; ++n) bias[n] = b1e[n0 + wn * 64 + n * 16 + lr];

#pragma unroll
    for (int m = 0; m < 4; ++m) {
        int rbase = wm * 64 + m * 16 + lhi * 4;
#pragma unroll
        for (int j = 0; j < 4; ++j) {
            int rl = rbase + j;
            if (rl < rows_here) {
                __bf16* hr = H + (size_t)(start + row0 + rl - hbase) * FFDIM + n0 + wn * 64;
#pragma unroll
                for (int n = 0; n < 4; ++n) {
                    float v = acc[m][n][j] + bias[n];
                    hr[n * 16 + lr] = (__bf16)gelu_exact(v);
                }
            }
        }
    }
}

// ---------------- GEMM2: out[token] += gate * (H @ W2[e] + b2[e]) ----------------
__global__ __launch_bounds__(256)
void gemm2_kernel(const __bf16* __restrict__ H, const float* __restrict__ W2,
                  const float* __restrict__ b2,
                  const int* __restrict__ perm, const float* __restrict__ gate_slot,
                  const int* __restrict__ counts, const int* __restrict__ offsets,
                  const int* __restrict__ tiletab,
                  float* __restrict__ out,
                  int e_arg, int c_arg, int CH)
{
    __shared__ __align__(16) char smem[(BM + BN) * 128]; // 32 KiB
    char* As = smem;
    char* Bs = smem + BM * 128;

    int e, start, cnt, hbase, row0, rows_here;
    if (!tile_header(counts, offsets, tiletab, e_arg, c_arg, CH, e, start, cnt, hbase, row0, rows_here))
        return;

    const float* W2e = W2 + (size_t)e * FFDIM * DDIM;
    const float* b2e = b2 + (size_t)e * DDIM;
    int n0 = blockIdx.x * BN;

    int tid = threadIdx.x;
    int lane = tid & 63;
    int wid = tid >> 6;
    int wm = wid >> 1, wn = wid & 1;
    int lr = lane & 15;
    int lhi = lane >> 4;

    int ar = tid >> 1, ach = tid & 1;
    bool aval = (ar < rows_here);
    const __bf16* hrow = H + (size_t)(aval ? (start + row0 + ar - hbase) : 0) * FFDIM + ach * 32;

    int bn = tid & 127, bkh = tid >> 7;
    const float* bcol = W2e + (size_t)bkh * 32 * DDIM + n0 + bn;

    f32x4 acc[4][4] = {};

    for (int k0 = 0; k0 < FFDIM; k0 += BK) {
        __syncthreads();
        // ---- stage A from H (already bf16): pure 16B copies ----
        {
            uint4 v[4];
            if (aval) {
                const uint4* p = (const uint4*)(hrow + k0);
#pragma unroll
                for (int i = 0; i < 4; ++i) v[i] = p[i];
            } else {
#pragma unroll
                for (int i = 0; i < 4; ++i) v[i] = make_uint4(0u, 0u, 0u, 0u);
            }
#pragma unroll
            for (int i = 0; i < 4; ++i)
                *(uint4*)(As + swz(ar, ach * 64 + i * 16)) = v[i];
        }
        // ---- stage B: W2 columns, transpose-free ----
        {
            float f[32];
            const float* p = bcol + (size_t)k0 * DDIM;
#pragma unroll
            for (int j = 0; j < 32; ++j) f[j] = p[(size_t)j * DDIM];
#pragma unroll
            for (int i = 0; i < 4; ++i) {
                BF8 pk;
#pragma unroll
                for (int q = 0; q < 8; ++q) pk.b[q] = (__bf16)f[i * 8 + q];
                *(uint4*)(Bs + swz(bn, bkh * 64 + i * 16)) = pk.u;
            }
        }
        __syncthreads();

#pragma unroll
        for (int kk = 0; kk < 2; ++kk) {
            bf16x8 af[4], bfr[4];
#pragma unroll
            for (int m = 0; m < 4; ++m)
                af[m] = *(const bf16x8*)(As + swz(wm * 64 + m * 16 + lr, kk * 64 + lhi * 16));
#pragma unroll
            for (int n = 0; n < 4; ++n)
                bfr[n] = *(const bf16x8*)(Bs + swz(wn * 64 + n * 16 + lr, kk * 64 + lhi * 16));
#pragma unroll
            for (int m = 0; m < 4; ++m)
#pragma unroll
                for (int n = 0; n < 4; ++n)
                    acc[m][n] = __builtin_amdgcn_mfma_f32_16x16x32_bf16(af[m], bfr[n], acc[m][n], 0, 0, 0);
        }
    }

    float bias[4];
#pragma unroll
    for (int n = 0; n < 4; ++n) bias[n] = b2e[n0 + wn * 64 + n * 16 + lr];

#pragma unroll
    for (int m = 0; m < 4; ++m) {
        int rbase = wm * 64 + m * 16 + lhi * 4;
#pragma unroll
        for (int j = 0; j < 4; ++j) {
            int rl = rbase + j;
            if (rl < rows_here) {
                int slot = start + row0 + rl;
                int token = perm[slot];
                float g = gate_slot[slot];
                float* orow = out + (size_t)token * DDIM + n0 + wn * 64;
#pragma unroll
                for (int n = 0; n < 4; ++n) {
                    float v = (acc[m][n][j] + bias[n]) * g;
                    atomicAdd(orow + n * 16 + lr, v);
                }
            }
        }
    }
}

extern "C" void kernel_launch(void* const* d_in, const int* in_sizes, int n_in,
                              void* d_out, int out_size, void* d_ws, size_t ws_size,
                              hipStream_t stream)
{
    const float* x  = (const float*)d_in[0];
    const float* Wr = (const float*)d_in[1];
    const float* W1 = (const float*)d_in[2];
    const float* b1 = (const float*)d_in[3];
    const float* W2 = (const float*)d_in[4];
    const float* b2 = (const float*)d_in[5];
    float* out = (float*)d_out;

    char* ws = (char*)d_ws;
    int* counts   = (int*)ws;                 // 8
    int* offsets  = counts + 8;               // 8
    int* cursors  = offsets + 8;              // 8
    int* tiletab  = cursors + 8;              // 2*MAXT
    int* idx2     = tiletab + 2 * MAXT;       // 2*NTOK
    float* gates2 = (float*)(idx2 + 2 * NTOK);// 2*NTOK
    int* perm     = (int*)(gates2 + 2 * NTOK);// NSLOT
    float* gate_slot = (float*)(perm + NSLOT);// NSLOT
    char* hraw = (char*)(gate_slot + NSLOT);
    size_t hoff = (((size_t)(hraw - ws)) + 255) & ~(size_t)255;
    __bf16* H = (__bf16*)(ws + hoff);
    size_t avail = ws_size > hoff ? ws_size - hoff : 0;
    size_t need_big = (size_t)NSLOT * FFDIM * 2;

    hipMemsetAsync(d_out, 0, (size_t)out_size * sizeof(float), stream);
    hipMemsetAsync(counts, 0, 8 * sizeof(int), stream);

    router_kernel<<<NTOK, 64, 0, stream>>>(x, Wr, idx2, gates2, counts);
    offsets_kernel<<<1, 1, 0, stream>>>(counts, offsets, cursors, tiletab);
    fill_kernel<<<NTOK / 256, 256, 0, stream>>>(idx2, gates2, offsets, cursors, perm, gate_slot);

    if (avail >= need_big) {
        dim3 g1(FFDIM / BN, MAXT, 1);
        gemm1_kernel<<<g1, 256, 0, stream>>>(x, W1, b1, perm, counts, offsets, tiletab, H, -1, 0, 0);
        dim3 g2(DDIM / BN, MAXT, 1);
        gemm2_kernel<<<g2, 256, 0, stream>>>(H, W2, b2, perm, gate_slot, counts, offsets, tiletab, out, -1, 0, 0);
    } else {
        size_t rowbytes = (size_t)FFDIM * 2;
        long long chl = (long long)((avail / rowbytes) / BM) * BM;
        int CH = (int)(chl > 2048 ? 2048 : chl);
        if (CH >= BM) {
            int nchunk = (NSLOT + CH - 1) / CH;
            for (int e = 0; e < NEXP; ++e) {
                for (int c = 0; c < nchunk; ++c) {
                    dim3 g1(FFDIM / BN, CH / BM, 1);
                    gemm1_kernel<<<g1, 256, 0, stream>>>(x, W1, b1, perm, counts, offsets, tiletab, H, e, c, CH);
                    dim3 g2(DDIM / BN, CH / BM, 1);
                    gemm2_kernel<<<g2, 256, 0, stream>>>(H, W2, b2, perm, gate_slot, counts, offsets, tiletab, out, e, c, CH);
                }
            }
        }
    }
}

// Round 3
// 856.203 us; speedup vs baseline: 2.2815x; 1.1756x over previous
//
#include <hip/hip_runtime.h>
#include <hip/hip_bf16.h>
#include <math.h>

#define NEXP 8
#define DDIM 1024
#define FFDIM 4096
#define NTOK 8192
#define NSLOT (NTOK * 2)
#define BM 128
#define BN 128
#define BK 64
#define MAXT ((NSLOT / BM) + NEXP) /* 136 worst-case row tiles */

typedef __attribute__((ext_vector_type(8))) __bf16 bf16x8;
typedef __attribute__((ext_vector_type(4))) float f32x4;

union BF8 { __bf16 b[8]; uint4 u; bf16x8 v; };

__device__ __forceinline__ float gelu_exact(float v) {
    return 0.5f * v * (1.0f + erff(v * 0.70710678118654752f));
}

// Swizzled byte offset inside a [rows][64 bf16] tile (128B rows).
__device__ __forceinline__ int swz(int row, int colb) {
    return row * 128 + (colb ^ ((row & 7) << 4));
}

// ---------------- router ----------------
__global__ __launch_bounds__(64)
void router_kernel(const float* __restrict__ x, const float* __restrict__ Wr,
                   int* __restrict__ idx2, float* __restrict__ gates2,
                   int* __restrict__ counts)
{
    int t = blockIdx.x;
    int lane = threadIdx.x;
    const float* xr = x + (size_t)t * DDIM;
    float acc[NEXP];
#pragma unroll
    for (int e = 0; e < NEXP; ++e) acc[e] = 0.f;
    for (int d = lane; d < DDIM; d += 64) {
        float xv = xr[d];
        const float* wrow = Wr + d * NEXP;
#pragma unroll
        for (int e = 0; e < NEXP; ++e) acc[e] += xv * wrow[e];
    }
#pragma unroll
    for (int e = 0; e < NEXP; ++e) {
        float v = acc[e];
        for (int off = 32; off > 0; off >>= 1) v += __shfl_xor(v, off, 64);
        acc[e] = v;
    }
    if (lane == 0) {
        float mx = acc[0];
#pragma unroll
        for (int e = 1; e < NEXP; ++e) mx = fmaxf(mx, acc[e]);
        float p[NEXP]; float s = 0.f;
#pragma unroll
        for (int e = 0; e < NEXP; ++e) { p[e] = expf(acc[e] - mx); s += p[e]; }
        float inv = 1.f / s;
#pragma unroll
        for (int e = 0; e < NEXP; ++e) p[e] *= inv;
        int i1 = 0; float p1 = p[0];
#pragma unroll
        for (int e = 1; e < NEXP; ++e) if (p[e] > p1) { p1 = p[e]; i1 = e; }
        int i2 = -1; float p2 = -1.f;
#pragma unroll
        for (int e = 0; e < NEXP; ++e) {
            if (e == i1) continue;
            if (p[e] > p2) { p2 = p[e]; i2 = e; }
        }
        float u = expf(p2 - p1);
        float den = 1.f + u;
        idx2[2 * t] = i1; idx2[2 * t + 1] = i2;
        gates2[2 * t] = 1.f / den; gates2[2 * t + 1] = u / den;
        atomicAdd(&counts[i1], 1);
        atomicAdd(&counts[i2], 1);
    }
}

// ---------------- offsets + tile table ----------------
__global__ void offsets_kernel(const int* __restrict__ counts, int* __restrict__ offsets,
                               int* __restrict__ cursors, int* __restrict__ tiletab)
{
    if (threadIdx.x != 0 || blockIdx.x != 0) return;
    int off = 0, idx = 0;
    for (int e = 0; e < NEXP; ++e) {
        offsets[e] = off;
        cursors[e] = 0;
        int nt = (counts[e] + BM - 1) / BM;
        for (int t = 0; t < nt; ++t) { tiletab[2 * idx] = e; tiletab[2 * idx + 1] = t; ++idx; }
        off += counts[e];
    }
    for (; idx < MAXT; ++idx) { tiletab[2 * idx] = -1; tiletab[2 * idx + 1] = 0; }
}

// ---------------- fill permutation ----------------
__global__ __launch_bounds__(256)
void fill_kernel(const int* __restrict__ idx2, const float* __restrict__ gates2,
                 const int* __restrict__ offsets, int* __restrict__ cursors,
                 int* __restrict__ perm, float* __restrict__ gate_slot)
{
    int t = blockIdx.x * 256 + threadIdx.x;
    if (t >= NTOK) return;
#pragma unroll
    for (int s = 0; s < 2; ++s) {
        int e = idx2[2 * t + s];
        int pos = atomicAdd(&cursors[e], 1);
        int slot = offsets[e] + pos;
        perm[slot] = t;
        gate_slot[slot] = gates2[2 * t + s];
    }
}

// ---------------- conversions ----------------
__global__ __launch_bounds__(256)
void convert_x_kernel(const float* __restrict__ x, __bf16* __restrict__ xb)
{
    size_t i = ((size_t)blockIdx.x * 256 + threadIdx.x) * 8;
    float4 a = *(const float4*)(x + i);
    float4 b = *(const float4*)(x + i + 4);
    BF8 pk;
    pk.b[0] = (__bf16)a.x; pk.b[1] = (__bf16)a.y; pk.b[2] = (__bf16)a.z; pk.b[3] = (__bf16)a.w;
    pk.b[4] = (__bf16)b.x; pk.b[5] = (__bf16)b.y; pk.b[6] = (__bf16)b.z; pk.b[7] = (__bf16)b.w;
    *(uint4*)(xb + i) = pk.u;
}

// W [E][K][N] fp32 row-major  ->  WT: per (e, ntile, ktile) a 16KB block that is
// byte-identical to the swizzled LDS Bs tile: row r = n_local, col k, 16B group
// gi at byte  r*128 + ((gi*16) ^ ((r&7)<<4)).
__global__ __launch_bounds__(256)
void convert_w_kernel(const float* __restrict__ W, __bf16* __restrict__ WT, int K, int N)
{
    int ktiles = K >> 6;
    int nt = blockIdx.x / ktiles;
    int kt = blockIdx.x % ktiles;
    int e = blockIdx.y;
    const float* We = W + (size_t)e * K * N;
    int t = threadIdx.x;
    int r = t & 127;      // n within tile
    int khalf = t >> 7;   // 0/1 (32 k each)
    const float* src = We + (size_t)(kt * 64 + khalf * 32) * N + nt * 128 + r;
    char* dst = (char*)WT + ((((size_t)e * (N >> 7) + nt) * ktiles + kt) << 14);
    float f[32];
#pragma unroll
    for (int j = 0; j < 32; ++j) f[j] = src[(size_t)j * N];
#pragma unroll
    for (int i = 0; i < 4; ++i) {
        BF8 pk;
#pragma unroll
        for (int q = 0; q < 8; ++q) pk.b[q] = (__bf16)f[i * 8 + q];
        int gi = khalf * 4 + i;
        *(uint4*)(dst + r * 128 + ((gi * 16) ^ ((r & 7) << 4))) = pk.u;
    }
}

// ---------------- shared tile-header logic ----------------
__device__ __forceinline__ bool tile_header(const int* counts, const int* offsets,
                                            const int* tiletab, int e_arg, int c_arg, int CH,
                                            int& e, int& start, int& cnt, int& hbase, int& row0,
                                            int& rows_here)
{
    int rowtile;
    if (e_arg >= 0) {
        e = e_arg;
        int cbase = c_arg * CH;
        cnt = counts[e] - cbase;
        if (cnt <= 0) return false;
        if (cnt > CH) cnt = CH;
        start = offsets[e] + cbase;
        rowtile = blockIdx.y;
        hbase = start;
    } else {
        e = tiletab[2 * blockIdx.y];
        if (e < 0) return false;
        rowtile = tiletab[2 * blockIdx.y + 1];
        start = offsets[e];
        cnt = counts[e];
        hbase = 0;
    }
    row0 = rowtile * BM;
    if (row0 >= cnt) return false;
    rows_here = cnt - row0;
    if (rows_here > BM) rows_here = BM;
    return true;
}

// ---------------- FAST GEMM1: H = gelu(Xb_gathered @ W1T[e] + b1[e]) ----------------
__global__ __launch_bounds__(256)
void gemm1_fast(const __bf16* __restrict__ xb, const __bf16* __restrict__ W1T,
                const float* __restrict__ b1,
                const int* __restrict__ perm, const int* __restrict__ counts,
                const int* __restrict__ offsets, const int* __restrict__ tiletab,
                __bf16* __restrict__ H, int e_arg, int c_arg, int CH)
{
    __shared__ __align__(16) char smem[(BM + BN) * 128]; // 32 KiB
    char* As = smem;
    char* Bs = smem + BM * 128;

    int e, start, cnt, hbase, row0, rows_here;
    if (!tile_header(counts, offsets, tiletab, e_arg, c_arg, CH, e, start, cnt, hbase, row0, rows_here))
        return;

    const float* b1e = b1 + (size_t)e * FFDIM;
    int nt = blockIdx.x;
    int n0 = nt * BN;
    const char* bsrc = (const char*)W1T + ((((size_t)e * (FFDIM >> 7) + nt) * (DDIM >> 6)) << 14);

    int tid = threadIdx.x;
    int lane = tid & 63;
    int wid = tid >> 6;
    int wm = wid >> 1, wn = wid & 1;
    int lr = lane & 15, lhi = lane >> 4;

    int ar = tid >> 1, ach = tid & 1;
    int token = -1;
    if (ar < rows_here) token = perm[start + row0 + ar];
    const __bf16* arow = xb + (size_t)(token < 0 ? 0 : token) * DDIM + ach * 32;

    int boff = wid * 4096 + lane * 16;

    f32x4 acc[4][4] = {};

    for (int kt = 0; kt < DDIM / BK; ++kt) {
        __syncthreads();
        // A: gathered bf16 rows -> swizzled LDS
        {
            uint4 v[4];
            if (token >= 0) {
                const uint4* p = (const uint4*)(arow + kt * BK);
#pragma unroll
                for (int i = 0; i < 4; ++i) v[i] = p[i];
            } else {
#pragma unroll
                for (int i = 0; i < 4; ++i) v[i] = make_uint4(0u, 0u, 0u, 0u);
            }
#pragma unroll
            for (int i = 0; i < 4; ++i)
                *(uint4*)(As + swz(ar, ach * 64 + i * 16)) = v[i];
        }
        // B: pre-swizzled 16KB tile -> linear LDS copy (1KB/wave/instr)
        {
            const char* tsrc = bsrc + ((size_t)kt << 14);
#pragma unroll
            for (int j = 0; j < 4; ++j) {
                uint4 v = *(const uint4*)(tsrc + j * 1024 + boff);
                *(uint4*)(Bs + j * 1024 + boff) = v;
            }
        }
        __syncthreads();

#pragma unroll
        for (int kk = 0; kk < 2; ++kk) {
            bf16x8 af[4], bfr[4];
#pragma unroll
            for (int m = 0; m < 4; ++m)
                af[m] = *(const bf16x8*)(As + swz(wm * 64 + m * 16 + lr, kk * 64 + lhi * 16));
#pragma unroll
            for (int n = 0; n < 4; ++n)
                bfr[n] = *(const bf16x8*)(Bs + swz(wn * 64 + n * 16 + lr, kk * 64 + lhi * 16));
#pragma unroll
            for (int m = 0; m < 4; ++m)
#pragma unroll
                for (int n = 0; n < 4; ++n)
                    acc[m][n] = __builtin_amdgcn_mfma_f32_16x16x32_bf16(af[m], bfr[n], acc[m][n], 0, 0, 0);
        }
    }

    float bias[4];
#pragma unroll
    for (int n = 0; n < 4; ++n) bias[n] = b1e[n0 + wn * 64 + n * 16 + lr];

#pragma unroll
    for (int m = 0; m < 4; ++m) {
        int rbase = wm * 64 + m * 16 + lhi * 4;
#pragma unroll
        for (int j = 0; j < 4; ++j) {
            int rl = rbase + j;
            if (rl < rows_here) {
                __bf16* hr = H + (size_t)(start + row0 + rl - hbase) * FFDIM + n0 + wn * 64;
#pragma unroll
                for (int n = 0; n < 4; ++n) {
                    float v = acc[m][n][j] + bias[n];
                    hr[n * 16 + lr] = (__bf16)gelu_exact(v);
                }
            }
        }
    }
}

// ---------------- FAST GEMM2: out[token] += gate * (H @ W2T[e] + b2[e]) ----------------
__global__ __launch_bounds__(256)
void gemm2_fast(const __bf16* __restrict__ H, const __bf16* __restrict__ W2T,
                const float* __restrict__ b2,
                const int* __restrict__ perm, const float* __restrict__ gate_slot,
                const int* __restrict__ counts, const int* __restrict__ offsets,
                const int* __restrict__ tiletab,
                float* __restrict__ out, int e_arg, int c_arg, int CH)
{
    __shared__ __align__(16) char smem[(BM + BN) * 128];
    char* As = smem;
    char* Bs = smem + BM * 128;

    int e, start, cnt, hbase, row0, rows_here;
    if (!tile_header(counts, offsets, tiletab, e_arg, c_arg, CH, e, start, cnt, hbase, row0, rows_here))
        return;

    const float* b2e = b2 + (size_t)e * DDIM;
    int nt = blockIdx.x;
    int n0 = nt * BN;
    const char* bsrc = (const char*)W2T + ((((size_t)e * (DDIM >> 7) + nt) * (FFDIM >> 6)) << 14);

    int tid = threadIdx.x;
    int lane = tid & 63;
    int wid = tid >> 6;
    int wm = wid >> 1, wn = wid & 1;
    int lr = lane & 15, lhi = lane >> 4;

    int ar = tid >> 1, ach = tid & 1;
    bool aval = (ar < rows_here);
    const __bf16* hrow = H + (size_t)(aval ? (start + row0 + ar - hbase) : 0) * FFDIM + ach * 32;

    int boff = wid * 4096 + lane * 16;

    f32x4 acc[4][4] = {};

    for (int kt = 0; kt < FFDIM / BK; ++kt) {
        __syncthreads();
        {
            uint4 v[4];
            if (aval) {
                const uint4* p = (const uint4*)(hrow + kt * BK);
#pragma unroll
                for (int i = 0; i < 4; ++i) v[i] = p[i];
            } else {
#pragma unroll
                for (int i = 0; i < 4; ++i) v[i] = make_uint4(0u, 0u, 0u, 0u);
            }
#pragma unroll
            for (int i = 0; i < 4; ++i)
                *(uint4*)(As + swz(ar, ach * 64 + i * 16)) = v[i];
        }
        {
            const char* tsrc = bsrc + ((size_t)kt << 14);
#pragma unroll
            for (int j = 0; j < 4; ++j) {
                uint4 v = *(const uint4*)(tsrc + j * 1024 + boff);
                *(uint4*)(Bs + j * 1024 + boff) = v;
            }
        }
        __syncthreads();

#pragma unroll
        for (int kk = 0; kk < 2; ++kk) {
            bf16x8 af[4], bfr[4];
#pragma unroll
            for (int m = 0; m < 4; ++m)
                af[m] = *(const bf16x8*)(As + swz(wm * 64 + m * 16 + lr, kk * 64 + lhi * 16));
#pragma unroll
            for (int n = 0; n < 4; ++n)
                bfr[n] = *(const bf16x8*)(Bs + swz(wn * 64 + n * 16 + lr, kk * 64 + lhi * 16));
#pragma unroll
            for (int m = 0; m < 4; ++m)
#pragma unroll
                for (int n = 0; n < 4; ++n)
                    acc[m][n] = __builtin_amdgcn_mfma_f32_16x16x32_bf16(af[m], bfr[n], acc[m][n], 0, 0, 0);
        }
    }

    float bias[4];
#pragma unroll
    for (int n = 0; n < 4; ++n) bias[n] = b2e[n0 + wn * 64 + n * 16 + lr];

#pragma unroll
    for (int m = 0; m < 4; ++m) {
        int rbase = wm * 64 + m * 16 + lhi * 4;
#pragma unroll
        for (int j = 0; j < 4; ++j) {
            int rl = rbase + j;
            if (rl < rows_here) {
                int slot = start + row0 + rl;
                int token = perm[slot];
                float g = gate_slot[slot];
                float* orow = out + (size_t)token * DDIM + n0 + wn * 64;
#pragma unroll
                for (int n = 0; n < 4; ++n) {
                    float v = (acc[m][n][j] + bias[n]) * g;
                    atomicAdd(orow + n * 16 + lr, v);
                }
            }
        }
    }
}

// ---------------- LEGACY kernels (fp32 weights, used only if ws too small) ----------------
__global__ __launch_bounds__(256)
void gemm1_legacy(const float* __restrict__ x, const float* __restrict__ W1,
                  const float* __restrict__ b1,
                  const int* __restrict__ perm, const int* __restrict__ counts,
                  const int* __restrict__ offsets, const int* __restrict__ tiletab,
                  __bf16* __restrict__ H, int e_arg, int c_arg, int CH)
{
    __shared__ __align__(16) char smem[(BM + BN) * 128];
    char* As = smem;
    char* Bs = smem + BM * 128;

    int e, start, cnt, hbase, row0, rows_here;
    if (!tile_header(counts, offsets, tiletab, e_arg, c_arg, CH, e, start, cnt, hbase, row0, rows_here))
        return;

    const float* W1e = W1 + (size_t)e * DDIM * FFDIM;
    const float* b1e = b1 + (size_t)e * FFDIM;
    int n0 = blockIdx.x * BN;

    int tid = threadIdx.x;
    int lane = tid & 63;
    int wid = tid >> 6;
    int wm = wid >> 1, wn = wid & 1;
    int lr = lane & 15, lhi = lane >> 4;

    int ar = tid >> 1, ach = tid & 1;
    int token = -1;
    if (ar < rows_here) token = perm[start + row0 + ar];
    const float* arow = x + (size_t)(token < 0 ? 0 : token) * DDIM + ach * 32;

    int bn = tid & 127, bkh = tid >> 7;
    const float* bcol = W1e + (size_t)bkh * 32 * FFDIM + n0 + bn;

    f32x4 acc[4][4] = {};

    for (int k0 = 0; k0 < DDIM; k0 += BK) {
        __syncthreads();
        {
            BF8 pk[4];
            if (token >= 0) {
                const float4* p = (const float4*)(arow + k0);
#pragma unroll
                for (int i = 0; i < 4; ++i) {
                    float4 v0 = p[2 * i], v1 = p[2 * i + 1];
                    pk[i].b[0] = (__bf16)v0.x; pk[i].b[1] = (__bf16)v0.y;
                    pk[i].b[2] = (__bf16)v0.z; pk[i].b[3] = (__bf16)v0.w;
                    pk[i].b[4] = (__bf16)v1.x; pk[i].b[5] = (__bf16)v1.y;
                    pk[i].b[6] = (__bf16)v1.z; pk[i].b[7] = (__bf16)v1.w;
                }
            } else {
#pragma unroll
                for (int i = 0; i < 4; ++i) pk[i].u = make_uint4(0u, 0u, 0u, 0u);
            }
#pragma unroll
            for (int i = 0; i < 4; ++i)
                *(uint4*)(As + swz(ar, ach * 64 + i * 16)) = pk[i].u;
        }
        {
            float f[32];
            const float* p = bcol + (size_t)k0 * FFDIM;
#pragma unroll
            for (int j = 0; j < 32; ++j) f[j] = p[(size_t)j * FFDIM];
#pragma unroll
            for (int i = 0; i < 4; ++i) {
                BF8 pk;
#pragma unroll
                for (int q = 0; q < 8; ++q) pk.b[q] = (__bf16)f[i * 8 + q];
                *(uint4*)(Bs + swz(bn, bkh * 64 + i * 16)) = pk.u;
            }
        }
        __syncthreads();

#pragma unroll
        for (int kk = 0; kk < 2; ++kk) {
            bf16x8 af[4], bfr[4];
#pragma unroll
            for (int m = 0; m < 4; ++m)
                af[m] = *(const bf16x8*)(As + swz(wm * 64 + m * 16 + lr, kk * 64 + lhi * 16));
#pragma unroll
            for (int n = 0; n < 4; ++n)
                bfr[n] = *(const bf16x8*)(Bs + swz(wn * 64 + n * 16 + lr, kk * 64 + lhi * 16));
#pragma unroll
            for (int m = 0; m < 4; ++m)
#pragma unroll
                for (int n = 0; n < 4; ++n)
                    acc[m][n] = __builtin_amdgcn_mfma_f32_16x16x32_bf16(af[m], bfr[n], acc[m][n], 0, 0, 0);
        }
    }

    float bias[4];
#pragma unroll
    for (int n = 0; n < 4; ++n) bias[n] = b1e[n0 + wn * 64 + n * 16 + lr];

#pragma unroll
    for (int m = 0; m < 4; ++m) {
        int rbase = wm * 64 + m * 16 + lhi * 4;
#pragma unroll
        for (int j = 0; j < 4; ++j) {
            int rl = rbase + j;
            if (rl < rows_here) {
                __bf16* hr = H + (size_t)(start + row0 + rl - hbase) * FFDIM + n0 + wn * 64;
#pragma unroll
                for (int n = 0; n < 4; ++n) {
                    float v = acc[m][n][j] + bias[n];
                    hr[n * 16 + lr] = (__bf16)gelu_exact(v);
                }
            }
        }
    }
}

__global__ __launch_bounds__(256)
void gemm2_legacy(const __bf16* __restrict__ H, const float* __restrict__ W2,
                  const float* __restrict__ b2,
                  const int* __restrict__ perm, const float* __restrict__ gate_slot,
                  const int* __restrict__ counts, const int* __restrict__ offsets,
                  const int* __restrict__ tiletab,
                  float* __restrict__ out, int e_arg, int c_arg, int CH)
{
    __shared__ __align__(16) char smem[(BM + BN) * 128];
    char* As = smem;
    char* Bs = smem + BM * 128;

    int e, start, cnt, hbase, row0, rows_here;
    if (!tile_header(counts, offsets, tiletab, e_arg, c_arg, CH, e, start, cnt, hbase, row0, rows_here))
        return;

    const float* W2e = W2 + (size_t)e * FFDIM * DDIM;
    const float* b2e = b2 + (size_t)e * DDIM;
    int n0 = blockIdx.x * BN;

    int tid = threadIdx.x;
    int lane = tid & 63;
    int wid = tid >> 6;
    int wm = wid >> 1, wn = wid & 1;
    int lr = lane & 15, lhi = lane >> 4;

    int ar = tid >> 1, ach = tid & 1;
    bool aval = (ar < rows_here);
    const __bf16* hrow = H + (size_t)(aval ? (start + row0 + ar - hbase) : 0) * FFDIM + ach * 32;

    int bn = tid & 127, bkh = tid >> 7;
    const float* bcol = W2e + (size_t)bkh * 32 * DDIM + n0 + bn;

    f32x4 acc[4][4] = {};

    for (int k0 = 0; k0 < FFDIM; k0 += BK) {
        __syncthreads();
        {
            uint4 v[4];
            if (aval) {
                const uint4* p = (const uint4*)(hrow + k0);
#pragma unroll
                for (int i = 0; i < 4; ++i) v[i] = p[i];
            } else {
#pragma unroll
                for (int i = 0; i < 4; ++i) v[i] = make_uint4(0u, 0u, 0u, 0u);
            }
#pragma unroll
            for (int i = 0; i < 4; ++i)
                *(uint4*)(As + swz(ar, ach * 64 + i * 16)) = v[i];
        }
        {
            float f[32];
            const float* p = bcol + (size_t)k0 * DDIM;
#pragma unroll
            for (int j = 0; j < 32; ++j) f[j] = p[(size_t)j * DDIM];
#pragma unroll
            for (int i = 0; i < 4; ++i) {
                BF8 pk;
#pragma unroll
                for (int q = 0; q < 8; ++q) pk.b[q] = (__bf16)f[i * 8 + q];
                *(uint4*)(Bs + swz(bn, bkh * 64 + i * 16)) = pk.u;
            }
        }
        __syncthreads();

#pragma unroll
        for (int kk = 0; kk < 2; ++kk) {
            bf16x8 af[4], bfr[4];
#pragma unroll
            for (int m = 0; m < 4; ++m)
                af[m] = *(const bf16x8*)(As + swz(wm * 64 + m * 16 + lr, kk * 64 + lhi * 16));
#pragma unroll
            for (int n = 0; n < 4; ++n)
                bfr[n] = *(const bf16x8*)(Bs + swz(wn * 64 + n * 16 + lr, kk * 64 + lhi * 16));
#pragma unroll
            for (int m = 0; m < 4; ++m)
#pragma unroll
                for (int n = 0; n < 4; ++n)
                    acc[m][n] = __builtin_amdgcn_mfma_f32_16x16x32_bf16(af[m], bfr[n], acc[m][n], 0, 0, 0);
        }
    }

    float bias[4];
#pragma unroll
    for (int n = 0; n < 4; ++n) bias[n] = b2e[n0 + wn * 64 + n * 16 + lr];

#pragma unroll
    for (int m = 0; m < 4; ++m) {
        int rbase = wm * 64 + m * 16 + lhi * 4;
#pragma unroll
        for (int j = 0; j < 4; ++j) {
            int rl = rbase + j;
            if (rl < rows_here) {
                int slot = start + row0 + rl;
                int token = perm[slot];
                float g = gate_slot[slot];
                float* orow = out + (size_t)token * DDIM + n0 + wn * 64;
#pragma unroll
                for (int n = 0; n < 4; ++n) {
                    float v = (acc[m][n][j] + bias[n]) * g;
                    atomicAdd(orow + n * 16 + lr, v);
                }
            }
        }
    }
}

extern "C" void kernel_launch(void* const* d_in, const int* in_sizes, int n_in,
                              void* d_out, int out_size, void* d_ws, size_t ws_size,
                              hipStream_t stream)
{
    const float* x  = (const float*)d_in[0];
    const float* Wr = (const float*)d_in[1];
    const float* W1 = (const float*)d_in[2];
    const float* b1 = (const float*)d_in[3];
    const float* W2 = (const float*)d_in[4];
    const float* b2 = (const float*)d_in[5];
    float* out = (float*)d_out;

    char* ws = (char*)d_ws;
    int* counts   = (int*)ws;
    int* offsets  = counts + 8;
    int* cursors  = offsets + 8;
    int* tiletab  = cursors + 8;               // 2*MAXT
    int* idx2     = tiletab + 2 * MAXT;        // 2*NTOK
    float* gates2 = (float*)(idx2 + 2 * NTOK); // 2*NTOK
    int* perm     = (int*)(gates2 + 2 * NTOK); // NSLOT
    float* gate_slot = (float*)(perm + NSLOT); // NSLOT
    char* hraw = (char*)(gate_slot + NSLOT);
    size_t small_end = (((size_t)(hraw - ws)) + 255) & ~(size_t)255;

    // fast-path layout
    __bf16* xb  = (__bf16*)(ws + small_end);                 // 16 MiB
    __bf16* W1T = xb + (size_t)NTOK * DDIM;                  // 64 MiB
    __bf16* W2T = W1T + (size_t)NEXP * DDIM * FFDIM;         // 64 MiB
    __bf16* Hf  = W2T + (size_t)NEXP * FFDIM * DDIM;
    size_t fast_off = small_end + ((size_t)NTOK * DDIM + 2 * (size_t)NEXP * DDIM * FFDIM) * 2;
    size_t availHf = ws_size > fast_off ? ws_size - fast_off : 0;
    size_t need_H = (size_t)NSLOT * FFDIM * 2;
    bool have_w = availHf >= (size_t)BM * FFDIM * 2 * 8; // weights fit + >=8MiB of H

    hipMemsetAsync(d_out, 0, (size_t)out_size * sizeof(float), stream);
    hipMemsetAsync(counts, 0, 8 * sizeof(int), stream);

    router_kernel<<<NTOK, 64, 0, stream>>>(x, Wr, idx2, gates2, counts);
    if (have_w) {
        convert_x_kernel<<<NTOK * DDIM / 2048, 256, 0, stream>>>(x, xb);
        convert_w_kernel<<<dim3((FFDIM / 128) * (DDIM / 64), NEXP), 256, 0, stream>>>(W1, W1T, DDIM, FFDIM);
        convert_w_kernel<<<dim3((DDIM / 128) * (FFDIM / 64), NEXP), 256, 0, stream>>>(W2, W2T, FFDIM, DDIM);
    }
    offsets_kernel<<<1, 1, 0, stream>>>(counts, offsets, cursors, tiletab);
    fill_kernel<<<NTOK / 256, 256, 0, stream>>>(idx2, gates2, offsets, cursors, perm, gate_slot);

    if (have_w && availHf >= need_H) {
        dim3 g1(FFDIM / BN, MAXT, 1);
        gemm1_fast<<<g1, 256, 0, stream>>>(xb, W1T, b1, perm, counts, offsets, tiletab, Hf, -1, 0, 0);
        dim3 g2(DDIM / BN, MAXT, 1);
        gemm2_fast<<<g2, 256, 0, stream>>>(Hf, W2T, b2, perm, gate_slot, counts, offsets, tiletab, out, -1, 0, 0);
    } else if (have_w) {
        long long chl = (long long)((availHf / ((size_t)FFDIM * 2)) / BM) * BM;
        int CH = (int)(chl > 4096 ? 4096 : chl);
        int nchunk = (NSLOT + CH - 1) / CH;
        for (int e = 0; e < NEXP; ++e) {
            for (int c = 0; c < nchunk; ++c) {
                dim3 g1(FFDIM / BN, CH / BM, 1);
                gemm1_fast<<<g1, 256, 0, stream>>>(xb, W1T, b1, perm, counts, offsets, tiletab, Hf, e, c, CH);
                dim3 g2(DDIM / BN, CH / BM, 1);
                gemm2_fast<<<g2, 256, 0, stream>>>(Hf, W2T, b2, perm, gate_slot, counts, offsets, tiletab, out, e, c, CH);
            }
        }
    } else {
        // legacy fp32-weight path; H lives right after the small region
        __bf16* H = (__bf16*)(ws + small_end);
        size_t avail = ws_size > small_end ? ws_size - small_end : 0;
        if (avail >= need_H) {
            dim3 g1(FFDIM / BN, MAXT, 1);
            gemm1_legacy<<<g1, 256, 0, stream>>>(x, W1, b1, perm, counts, offsets, tiletab, H, -1, 0, 0);
            dim3 g2(DDIM / BN, MAXT, 1);
            gemm2_legacy<<<g2, 256, 0, stream>>>(H, W2, b2, perm, gate_slot, counts, offsets, tiletab, out, -1, 0, 0);
        } else {
            long long chl = (long long)((avail / ((size_t)FFDIM * 2)) / BM) * BM;
            int CH = (int)(chl > 2048 ? 2048 : chl);
            if (CH >= BM) {
                int nchunk = (NSLOT + CH - 1) / CH;
                for (int e = 0; e < NEXP; ++e) {
                    for (int c = 0; c < nchunk; ++c) {
                        dim3 g1(FFDIM / BN, CH / BM, 1);
                        gemm1_legacy<<<g1, 256, 0, stream>>>(x, W1, b1, perm, counts, offsets, tiletab, H, e, c, CH);
                        dim3 g2(DDIM / BN, CH / BM, 1);
                        gemm2_legacy<<<g2, 256, 0, stream>>>(H, W2, b2, perm, gate_slot, counts, offsets, tiletab, out, e, c, CH);
                    }
                }
            }
        }
    }
}